// Round 1
// baseline (1938.829 us; speedup 1.0000x reference)
//
#include <hip/hip_runtime.h>

#define MEMORY_LENGTH 32
#define N_TARGETS 3
#define T_STEPS 1000
#define DT 0.1f
#define HIDDEN 128
#define N_AGENTS 1024

// One wave (64 lanes) per agent. Lane l owns W1 rows l and l+64 in VGPRs.
// History is a doubled ring (64 x float4) in LDS; window [base, base+31]
// always holds states at times t, t-1, ..., t-31 (newest first).
__global__ __launch_bounds__(64, 1)
void sim_kernel(const float* __restrict__ target_pos,
                const float* __restrict__ logsigma,
                const float* __restrict__ x_inits,
                const float* __restrict__ W1,
                const float* __restrict__ b1,
                const float* __restrict__ W2,
                const float* __restrict__ b2,
                float2* __restrict__ ws) {
    const int agent = blockIdx.x;
    const int l = threadIdx.x;  // 0..63

    __shared__ float4 ring[64];

    // Targets (uniform across lanes)
    const float tx0 = target_pos[0], ty0 = target_pos[1];
    const float tx1 = target_pos[2], ty1 = target_pos[3];
    const float tx2 = target_pos[4], ty2 = target_pos[5];
    const float is0 = 1.0f / expf(logsigma[0]);
    const float is1 = 1.0f / expf(logsigma[1]);
    const float is2 = 1.0f / expf(logsigma[2]);

    // W1 rows l and l+64 into registers (fully unrolled -> stays in VGPRs)
    float wl[128], wh[128];
    const float4* W1v = (const float4*)W1;
    #pragma unroll
    for (int i = 0; i < 32; ++i) {
        float4 v = W1v[l * 32 + i];
        wl[4*i] = v.x; wl[4*i+1] = v.y; wl[4*i+2] = v.z; wl[4*i+3] = v.w;
    }
    #pragma unroll
    for (int i = 0; i < 32; ++i) {
        float4 v = W1v[(l + 64) * 32 + i];
        wh[4*i] = v.x; wh[4*i+1] = v.y; wh[4*i+2] = v.z; wh[4*i+3] = v.w;
    }
    const float b1l = b1[l], b1h = b1[l + 64];
    const float w2a0 = W2[l],       w2a1 = W2[l + 64];
    const float w2b0 = W2[128 + l], w2b1 = W2[128 + l + 64];
    const float b2x = b2[0], b2y = b2[1];

    float x  = x_inits[3 * agent];
    float y  = x_inits[3 * agent + 1];
    float th = x_inits[3 * agent + 2];

    auto conc = [&](float px, float py) {
        float dx0 = px - tx0, dy0 = py - ty0;
        float dx1 = px - tx1, dy1 = py - ty1;
        float dx2 = px - tx2, dy2 = py - ty2;
        float c  = is0 * __expf(-(dx0*dx0 + dy0*dy0) * is0);
        c       += is1 * __expf(-(dx1*dx1 + dy1*dy1) * is1);
        c       += is2 * __expf(-(dx2*dx2 + dy2*dy2) * is2);
        return c;
    };

    // Initial history: all 64 slots = initial state
    float c0 = conc(x, y);
    ring[l] = make_float4(x, y, th, c0);
    __syncthreads();

    int base = 32;          // window [32..63] at t=0
    float S_c = 0.f, S_u = 0.f;

    for (int t = 0; t < T_STEPS; ++t) {
        // ---- layer 1: h[l], h[l+64] ----
        float a0x = 0.f, a0y = 0.f, a0z = 0.f, a0w = b1l;
        float a1x = 0.f, a1y = 0.f, a1z = 0.f, a1w = b1h;
        #pragma unroll
        for (int m = 0; m < 32; ++m) {
            float4 e = ring[base + m];   // broadcast read (conflict-free)
            a0x = fmaf(wl[3*m],     e.x, a0x);
            a0y = fmaf(wl[3*m + 1], e.y, a0y);
            a0z = fmaf(wl[3*m + 2], e.z, a0z);
            a0w = fmaf(wl[96 + m],  e.w, a0w);
            a1x = fmaf(wh[3*m],     e.x, a1x);
            a1y = fmaf(wh[3*m + 1], e.y, a1y);
            a1z = fmaf(wh[3*m + 2], e.z, a1z);
            a1w = fmaf(wh[96 + m],  e.w, a1w);
        }
        float h0 = fmaxf((a0x + a0y) + (a0z + a0w), 0.f);
        float h1 = fmaxf((a1x + a1y) + (a1z + a1w), 0.f);

        // ---- layer 2: butterfly reduce over 64 lanes ----
        float p0 = fmaf(w2a0, h0, w2a1 * h1);
        float p1 = fmaf(w2b0, h0, w2b1 * h1);
        #pragma unroll
        for (int off = 32; off > 0; off >>= 1) {
            p0 += __shfl_xor(p0, off);
            p1 += __shfl_xor(p1, off);
        }

        // ---- controls + dynamics (uniform, redundant on all lanes) ----
        float v = tanhf(p0 + b2x);
        float w = tanhf(p1 + b2y);
        S_u += v * v + w * w;

        float sn, cs;
        sincosf(th, &sn, &cs);
        x  = fmaf(DT * v, cs, x);
        y  = fmaf(DT * v, sn, y);
        th = fmaf(DT, w, th);

        float cn = conc(x, y);
        S_c += cn;

        // ---- push new entry into ring (dual write for unwrapped window) ----
        int q = (base - 1) & 31;
        if (l == 0) {
            float4 e = make_float4(x, y, th, cn);
            ring[q]      = e;
            ring[q + 32] = e;
        }
        __syncthreads();   // single-wave block: cheap fence
        base = q;
    }

    if (l == 0) ws[agent] = make_float2(S_c, S_u);
}

__global__ void reduce_kernel(const float2* __restrict__ ws,
                              float* __restrict__ out) {
    const int tid = threadIdx.x;  // 256 threads
    float sc = 0.f, su = 0.f;
    for (int i = tid; i < N_AGENTS; i += 256) {
        float2 v = ws[i];
        sc += v.x;
        su += v.y;
    }
    #pragma unroll
    for (int off = 32; off > 0; off >>= 1) {
        sc += __shfl_xor(sc, off);
        su += __shfl_xor(su, off);
    }
    __shared__ float2 part[4];
    int wave = tid >> 6;
    if ((tid & 63) == 0) part[wave] = make_float2(sc, su);
    __syncthreads();
    if (tid == 0) {
        float SC = part[0].x + part[1].x + part[2].x + part[3].x;
        float SU = part[0].y + part[1].y + part[2].y + part[3].y;
        const float invNT  = 1.0f / (float)(N_AGENTS * T_STEPS);
        const float invNT2 = 1.0f / (float)(N_AGENTS * T_STEPS * 2);
        out[0] = -SC * invNT + SU * invNT2;
    }
}

extern "C" void kernel_launch(void* const* d_in, const int* in_sizes, int n_in,
                              void* d_out, int out_size, void* d_ws, size_t ws_size,
                              hipStream_t stream) {
    const float* target_pos = (const float*)d_in[0];
    const float* logsigma   = (const float*)d_in[1];
    const float* x_inits    = (const float*)d_in[2];
    const float* W1         = (const float*)d_in[3];
    const float* b1         = (const float*)d_in[4];
    const float* W2         = (const float*)d_in[5];
    const float* b2         = (const float*)d_in[6];
    float2* ws = (float2*)d_ws;

    sim_kernel<<<N_AGENTS, 64, 0, stream>>>(target_pos, logsigma, x_inits,
                                            W1, b1, W2, b2, ws);
    reduce_kernel<<<1, 256, 0, stream>>>(ws, (float*)d_out);
}

// Round 2
// 1359.741 us; speedup vs baseline: 1.4259x; 1.4259x over previous
//
#include <hip/hip_runtime.h>

#define MEMORY_LENGTH 32
#define T_STEPS 1000
#define DT 0.1f
#define HIDDEN 128
#define N_AGENTS 1024

// tanh(x) = 1 - 2/(exp(2x)+1); exact at +/-inf, ~1e-7 rel error.
__device__ __forceinline__ float tanh_fast(float x) {
    float e = __expf(2.0f * x);
    return 1.0f - 2.0f * __builtin_amdgcn_rcpf(e + 1.0f);
}

// One agent per block of 128 threads (2 waves). Lane tid owns W1 row tid
// (128 floats in VGPRs -> no spill at 2 waves/SIMD budget of 256 VGPRs).
// Each wave keeps a PRIVATE doubled history ring in LDS (written and read
// only by itself -> no barrier needed for the ring). The only cross-wave
// traffic is the 2-float layer-2 partial, exchanged through parity-double-
// buffered LDS with ONE __syncthreads per step.
__global__ __launch_bounds__(128, 2)
void sim_kernel(const float* __restrict__ target_pos,
                const float* __restrict__ logsigma,
                const float* __restrict__ x_inits,
                const float* __restrict__ W1,
                const float* __restrict__ b1,
                const float* __restrict__ W2,
                const float* __restrict__ b2,
                float2* __restrict__ ws) {
    const int agent = blockIdx.x;
    const int tid  = threadIdx.x;   // 0..127 = W1 row index
    const int wave = tid >> 6;      // 0 or 1
    const int lane = tid & 63;

    __shared__ float4 ring[2][64];  // per-wave private doubled ring
    __shared__ float2 part[2][2];   // [step parity][wave] layer-2 partials

    const float tx0 = target_pos[0], ty0 = target_pos[1];
    const float tx1 = target_pos[2], ty1 = target_pos[3];
    const float tx2 = target_pos[4], ty2 = target_pos[5];
    const float is0 = 1.0f / expf(logsigma[0]);
    const float is1 = 1.0f / expf(logsigma[1]);
    const float is2 = 1.0f / expf(logsigma[2]);

    // W1 row `tid` into registers: 96 position weights + 32 conc weights.
    float wp[96], wc[32];
    {
        const float4* W1v = (const float4*)(W1 + tid * 128);
        #pragma unroll
        for (int i = 0; i < 24; ++i) {
            float4 v = W1v[i];
            wp[4*i] = v.x; wp[4*i+1] = v.y; wp[4*i+2] = v.z; wp[4*i+3] = v.w;
        }
        #pragma unroll
        for (int i = 0; i < 8; ++i) {
            float4 v = W1v[24 + i];
            wc[4*i] = v.x; wc[4*i+1] = v.y; wc[4*i+2] = v.z; wc[4*i+3] = v.w;
        }
    }
    const float b1r = b1[tid];
    const float w2a = W2[tid];           // W2 row 0
    const float w2b = W2[HIDDEN + tid];  // W2 row 1
    const float b2x = b2[0], b2y = b2[1];

    float x  = x_inits[3 * agent];
    float y  = x_inits[3 * agent + 1];
    float th = x_inits[3 * agent + 2];

    auto conc = [&](float px, float py) {
        float dx0 = px - tx0, dy0 = py - ty0;
        float dx1 = px - tx1, dy1 = py - ty1;
        float dx2 = px - tx2, dy2 = py - ty2;
        float c  = is0 * __expf(-(dx0*dx0 + dy0*dy0) * is0);
        c       += is1 * __expf(-(dx1*dx1 + dy1*dy1) * is1);
        c       += is2 * __expf(-(dx2*dx2 + dy2*dy2) * is2);
        return c;
    };

    // Initial history: every slot = initial state (each wave fills its ring).
    float c0 = conc(x, y);
    ring[wave][lane] = make_float4(x, y, th, c0);
    __syncthreads();

    int base = 32;                 // window [base, base+31], newest first
    float S_c = 0.f, S_u = 0.f;

    for (int t = 0; t < T_STEPS; ++t) {
        // ---- layer 1: h[tid] ----
        float ax = 0.f, ay = 0.f, az = 0.f, aw = b1r;
        #pragma unroll
        for (int m = 0; m < 32; ++m) {
            float4 e = ring[wave][base + m];   // broadcast, conflict-free
            ax = fmaf(wp[3*m],     e.x, ax);
            ay = fmaf(wp[3*m + 1], e.y, ay);
            az = fmaf(wp[3*m + 2], e.z, az);
            aw = fmaf(wc[m],       e.w, aw);
        }
        float h = fmaxf((ax + ay) + (az + aw), 0.f);

        // ---- layer 2: per-wave butterfly, then cross-wave via LDS ----
        float p0 = w2a * h;
        float p1 = w2b * h;
        #pragma unroll
        for (int off = 32; off > 0; off >>= 1) {
            p0 += __shfl_xor(p0, off);
            p1 += __shfl_xor(p1, off);
        }
        if (lane == 0) part[t & 1][wave] = make_float2(p0, p1);
        __syncthreads();
        float P0 = part[t & 1][0].x + part[t & 1][1].x;
        float P1 = part[t & 1][0].y + part[t & 1][1].y;

        // ---- controls + dynamics (uniform on all lanes) ----
        float v = tanh_fast(P0 + b2x);
        float w = tanh_fast(P1 + b2y);
        S_u += v * v + w * w;

        float sn = __sinf(th), cs = __cosf(th);
        x  = fmaf(DT * v, cs, x);
        y  = fmaf(DT * v, sn, y);
        th = fmaf(DT, w, th);

        float cn = conc(x, y);
        S_c += cn;

        // ---- push into own ring (dual write keeps window unwrapped) ----
        int q = (base - 1) & 31;
        if (lane == 0) {
            float4 e = make_float4(x, y, th, cn);
            ring[wave][q]      = e;
            ring[wave][q + 32] = e;
        }
        base = q;
        // no second barrier: ring is wave-private, same-wave LDS RAW is
        // ordered by the compiler's lgkmcnt waits.
    }

    if (tid == 0) ws[agent] = make_float2(S_c, S_u);
}

__global__ void reduce_kernel(const float2* __restrict__ ws,
                              float* __restrict__ out) {
    const int tid = threadIdx.x;  // 256 threads
    float sc = 0.f, su = 0.f;
    for (int i = tid; i < N_AGENTS; i += 256) {
        float2 v = ws[i];
        sc += v.x;
        su += v.y;
    }
    #pragma unroll
    for (int off = 32; off > 0; off >>= 1) {
        sc += __shfl_xor(sc, off);
        su += __shfl_xor(su, off);
    }
    __shared__ float2 partw[4];
    int wave = tid >> 6;
    if ((tid & 63) == 0) partw[wave] = make_float2(sc, su);
    __syncthreads();
    if (tid == 0) {
        float SC = partw[0].x + partw[1].x + partw[2].x + partw[3].x;
        float SU = partw[0].y + partw[1].y + partw[2].y + partw[3].y;
        const float invNT  = 1.0f / (float)(N_AGENTS * T_STEPS);
        const float invNT2 = 1.0f / (float)(N_AGENTS * T_STEPS * 2);
        out[0] = -SC * invNT + SU * invNT2;
    }
}

extern "C" void kernel_launch(void* const* d_in, const int* in_sizes, int n_in,
                              void* d_out, int out_size, void* d_ws, size_t ws_size,
                              hipStream_t stream) {
    const float* target_pos = (const float*)d_in[0];
    const float* logsigma   = (const float*)d_in[1];
    const float* x_inits    = (const float*)d_in[2];
    const float* W1         = (const float*)d_in[3];
    const float* b1         = (const float*)d_in[4];
    const float* W2         = (const float*)d_in[5];
    const float* b2         = (const float*)d_in[6];
    float2* ws = (float2*)d_ws;

    sim_kernel<<<N_AGENTS, 128, 0, stream>>>(target_pos, logsigma, x_inits,
                                             W1, b1, W2, b2, ws);
    reduce_kernel<<<1, 256, 0, stream>>>(ws, (float*)d_out);
}

// Round 3
// 1333.160 us; speedup vs baseline: 1.4543x; 1.0199x over previous
//
#include <hip/hip_runtime.h>

#define MEMORY_LENGTH 32
#define T_STEPS 1000
#define DT 0.1f
#define HIDDEN 128
#define N_AGENTS 1024

// tanh(x) = 1 - 2/(exp(2x)+1); exact at +/-inf, ~1e-7 rel error.
__device__ __forceinline__ float tanh_fast(float x) {
    float e = __expf(2.0f * x);
    return 1.0f - 2.0f * __builtin_amdgcn_rcpf(e + 1.0f);
}

// One agent per block of 128 threads (2 waves). Lane tid owns W1 row tid:
// 128 weight floats PINNED into VGPRs (inline-asm makes them opaque so the
// backend cannot rematerialize the loads inside the t-loop, and
// amdgpu_waves_per_eu(2,2) pins the occupancy target so the 256-VGPR/wave
// budget is actually used). Each wave keeps a PRIVATE doubled history ring
// in LDS; only cross-wave traffic is the 2-float layer-2 partial through
// parity-double-buffered LDS with ONE __syncthreads per step.
__global__ __launch_bounds__(128)
__attribute__((amdgpu_waves_per_eu(2, 2)))
void sim_kernel(const float* __restrict__ target_pos,
                const float* __restrict__ logsigma,
                const float* __restrict__ x_inits,
                const float* __restrict__ W1,
                const float* __restrict__ b1,
                const float* __restrict__ W2,
                const float* __restrict__ b2,
                float2* __restrict__ ws) {
    const int agent = blockIdx.x;
    const int tid  = threadIdx.x;   // 0..127 = W1 row index
    const int wave = tid >> 6;      // 0 or 1
    const int lane = tid & 63;

    __shared__ float4 ring[2][64];  // per-wave private doubled ring
    __shared__ float2 part[2][2];   // [step parity][wave] layer-2 partials

    const float tx0 = target_pos[0], ty0 = target_pos[1];
    const float tx1 = target_pos[2], ty1 = target_pos[3];
    const float tx2 = target_pos[4], ty2 = target_pos[5];
    const float is0 = 1.0f / expf(logsigma[0]);
    const float is1 = 1.0f / expf(logsigma[1]);
    const float is2 = 1.0f / expf(logsigma[2]);

    // W1 row `tid` into registers: 96 position weights + 32 conc weights.
    float wp[96], wc[32];
    {
        const float4* W1v = (const float4*)(W1 + tid * 128);
        #pragma unroll
        for (int i = 0; i < 24; ++i) {
            float4 v = W1v[i];
            wp[4*i] = v.x; wp[4*i+1] = v.y; wp[4*i+2] = v.z; wp[4*i+3] = v.w;
        }
        #pragma unroll
        for (int i = 0; i < 8; ++i) {
            float4 v = W1v[24 + i];
            wc[4*i] = v.x; wc[4*i+1] = v.y; wc[4*i+2] = v.z; wc[4*i+3] = v.w;
        }
    }
    // Pin every weight into a VGPR: opaque to rematerialization.
    #pragma unroll
    for (int i = 0; i < 96; ++i) asm volatile("" : "+v"(wp[i]));
    #pragma unroll
    for (int i = 0; i < 32; ++i) asm volatile("" : "+v"(wc[i]));

    const float b1r = b1[tid];
    const float w2a = W2[tid];           // W2 row 0
    const float w2b = W2[HIDDEN + tid];  // W2 row 1
    const float b2x = b2[0], b2y = b2[1];

    float x  = x_inits[3 * agent];
    float y  = x_inits[3 * agent + 1];
    float th = x_inits[3 * agent + 2];

    auto conc = [&](float px, float py) {
        float dx0 = px - tx0, dy0 = py - ty0;
        float dx1 = px - tx1, dy1 = py - ty1;
        float dx2 = px - tx2, dy2 = py - ty2;
        float c  = is0 * __expf(-(dx0*dx0 + dy0*dy0) * is0);
        c       += is1 * __expf(-(dx1*dx1 + dy1*dy1) * is1);
        c       += is2 * __expf(-(dx2*dx2 + dy2*dy2) * is2);
        return c;
    };

    // Initial history: every slot = initial state (each wave fills its ring).
    float c0 = conc(x, y);
    ring[wave][lane] = make_float4(x, y, th, c0);
    __syncthreads();

    int base = 32;                 // window [base, base+31], newest first
    float S_c = 0.f, S_u = 0.f;

    for (int t = 0; t < T_STEPS; ++t) {
        // ---- layer 1: h[tid] ----
        float ax = 0.f, ay = 0.f, az = 0.f, aw = b1r;
        #pragma unroll
        for (int m = 0; m < 32; ++m) {
            float4 e = ring[wave][base + m];   // broadcast, conflict-free
            ax = fmaf(wp[3*m],     e.x, ax);
            ay = fmaf(wp[3*m + 1], e.y, ay);
            az = fmaf(wp[3*m + 2], e.z, az);
            aw = fmaf(wc[m],       e.w, aw);
        }
        float h = fmaxf((ax + ay) + (az + aw), 0.f);

        // ---- layer 2: per-wave butterfly, then cross-wave via LDS ----
        float p0 = w2a * h;
        float p1 = w2b * h;
        #pragma unroll
        for (int off = 32; off > 0; off >>= 1) {
            p0 += __shfl_xor(p0, off);
            p1 += __shfl_xor(p1, off);
        }
        if (lane == 0) part[t & 1][wave] = make_float2(p0, p1);
        __syncthreads();
        float P0 = part[t & 1][0].x + part[t & 1][1].x;
        float P1 = part[t & 1][0].y + part[t & 1][1].y;

        // ---- controls + dynamics (uniform on all lanes) ----
        float v = tanh_fast(P0 + b2x);
        float w = tanh_fast(P1 + b2y);
        S_u += v * v + w * w;

        float sn = __sinf(th), cs = __cosf(th);
        x  = fmaf(DT * v, cs, x);
        y  = fmaf(DT * v, sn, y);
        th = fmaf(DT, w, th);

        float cn = conc(x, y);
        S_c += cn;

        // ---- push into own ring (dual write keeps window unwrapped) ----
        int q = (base - 1) & 31;
        if (lane == 0) {
            float4 e = make_float4(x, y, th, cn);
            ring[wave][q]      = e;
            ring[wave][q + 32] = e;
        }
        base = q;
        // no second barrier: ring is wave-private, same-wave LDS RAW is
        // ordered by the compiler's lgkmcnt waits.
    }

    if (tid == 0) ws[agent] = make_float2(S_c, S_u);
}

__global__ void reduce_kernel(const float2* __restrict__ ws,
                              float* __restrict__ out) {
    const int tid = threadIdx.x;  // 256 threads
    float sc = 0.f, su = 0.f;
    for (int i = tid; i < N_AGENTS; i += 256) {
        float2 v = ws[i];
        sc += v.x;
        su += v.y;
    }
    #pragma unroll
    for (int off = 32; off > 0; off >>= 1) {
        sc += __shfl_xor(sc, off);
        su += __shfl_xor(su, off);
    }
    __shared__ float2 partw[4];
    int wave = tid >> 6;
    if ((tid & 63) == 0) partw[wave] = make_float2(sc, su);
    __syncthreads();
    if (tid == 0) {
        float SC = partw[0].x + partw[1].x + partw[2].x + partw[3].x;
        float SU = partw[0].y + partw[1].y + partw[2].y + partw[3].y;
        const float invNT  = 1.0f / (float)(N_AGENTS * T_STEPS);
        const float invNT2 = 1.0f / (float)(N_AGENTS * T_STEPS * 2);
        out[0] = -SC * invNT + SU * invNT2;
    }
}

extern "C" void kernel_launch(void* const* d_in, const int* in_sizes, int n_in,
                              void* d_out, int out_size, void* d_ws, size_t ws_size,
                              hipStream_t stream) {
    const float* target_pos = (const float*)d_in[0];
    const float* logsigma   = (const float*)d_in[1];
    const float* x_inits    = (const float*)d_in[2];
    const float* W1         = (const float*)d_in[3];
    const float* b1         = (const float*)d_in[4];
    const float* W2         = (const float*)d_in[5];
    const float* b2         = (const float*)d_in[6];
    float2* ws = (float2*)d_ws;

    sim_kernel<<<N_AGENTS, 128, 0, stream>>>(target_pos, logsigma, x_inits,
                                             W1, b1, W2, b2, ws);
    reduce_kernel<<<1, 256, 0, stream>>>(ws, (float*)d_out);
}